// Round 3
// baseline (294.027 us; speedup 1.0000x reference)
//
#include <hip/hip_runtime.h>

typedef unsigned short u16;
typedef unsigned int   u32;
typedef float  f32x16 __attribute__((ext_vector_type(16)));
typedef __bf16 bf16x8 __attribute__((ext_vector_type(8)));

#define B_N   8
#define T_N   1500
#define D_N   512
#define K_N   4096
#define NTOK  12000
#define STRD  320

// ---- workspace byte offsets (total ~28.0 MB) ----
#define X2S_OFF     0u          // 12000 f
#define C2_OFF      49152u      // 4096 f
#define FEATP_OFF   65536u      // 375 f
#define TRIPP_OFF   67584u      // 375 f
#define SOFTP2_OFF  69632u      // 47 f
#define COMMP2_OFF  70656u      // 47 f
#define STATEP_OFF  71680u      // 5*2*12000 f = 480000 B
#define SBF_OFF     557056u     // 375 tiles * 32KB
#define TBF_OFF     (557056u + 12288000u)
#define CBBF_OFF    (557056u + 24576000u)   // 4096*512 bf16 = 4 MB

// ---- global bf16 layouts, in 16B chunks of 8 consecutive k ----
// sbf/tbf: chunk = (tt*32 + ks)*64 + kh*32 + sp    (token=tt*32+sp, k=ks*16+kh*8+j)
// cbbf:    chunk = ((((ch*4+ci)*16 + kc)*16 + ctg)*2 + ks2)*64 + kh*32 + sp
//          (code=ch*2048+ci*512+ctg*32+sp, k=kc*32+ks2*16+kh*8+j)
// => every global fragment load / global_load_lds / ds_read_b128 is base + lane*16

__device__ __forceinline__ u16 f2bf(float x){
  u32 u = __float_as_uint(x);
  u32 r = (u + 0x7fffu + ((u >> 16) & 1u)) >> 16;   // round-nearest-even
  return (u16)r;
}

__device__ __forceinline__ void gl_lds16(const void* g, void* l){
  __builtin_amdgcn_global_load_lds(
      (__attribute__((address_space(1))) void*)(g),
      (__attribute__((address_space(3))) void*)(l),
      16, 0, 0);
}

__device__ __forceinline__ void merge_state(float& m, float& Z, float om, float oZ){
  float nm = fmaxf(m, om);
  Z = Z*__expf(m - nm) + oZ*__expf(om - nm);
  m = nm;
}
__device__ __forceinline__ void merge_stateT(float& m, float& Z, float& A,
                                             float om, float oZ, float oA){
  float nm = fmaxf(m, om);
  float e0 = __expf(m - nm), e1 = __expf(om - nm);
  Z = Z*e0 + oZ*e1; A = A*e0 + oA*e1; m = nm;
}

// ============ prep 1: 32-token tile per block; coalesced permuted stores ============
__global__ __launch_bounds__(256) void prep_feat_kernel(
    const float* __restrict__ s, const float* __restrict__ t,
    const int* __restrict__ lengths,
    u16* __restrict__ sbf, u16* __restrict__ tbf,
    float* __restrict__ x2s, float* __restrict__ featP, float* __restrict__ tripP)
{
  const int tid = threadIdx.x;
  const int w = tid >> 6, lane = tid & 63;
  const int kh = lane >> 5, sp = lane & 31;
  const int tt = blockIdx.x;
  const int n = tt*32 + sp;
  const int b = n / T_N, tok = n - b*T_N;
  const int nr = ((b+7)&7)*T_N + tok;            // roll(teacher,+1,axis=0)
  const float* srow = s + (size_t)n  * D_N;
  const float* trow = t + (size_t)n  * D_N;
  const float* rrow = t + (size_t)nr * D_N;

  float x2 = 0.f, sd2 = 0.f, nd2 = 0.f;
#pragma unroll
  for (int j = 0; j < 8; ++j){
    const int ks = w*8 + j;
    const int k0 = ks*16 + kh*8;
    float4 s0 = *(const float4*)(srow + k0), s1 = *(const float4*)(srow + k0 + 4);
    float4 t0 = *(const float4*)(trow + k0), t1 = *(const float4*)(trow + k0 + 4);
    float4 r0 = *(const float4*)(rrow + k0), r1 = *(const float4*)(rrow + k0 + 4);
    float sv[8] = {s0.x,s0.y,s0.z,s0.w,s1.x,s1.y,s1.z,s1.w};
    float tv[8] = {t0.x,t0.y,t0.z,t0.w,t1.x,t1.y,t1.z,t1.w};
    float rv[8] = {r0.x,r0.y,r0.z,r0.w,r1.x,r1.y,r1.z,r1.w};
    u16 sb[8], tb[8];
#pragma unroll
    for (int i = 0; i < 8; ++i){
      float d = sv[i] - tv[i]; sd2 += d*d;
      x2 += sv[i]*sv[i];
      float e = sv[i] - rv[i]; nd2 += e*e;
      sb[i] = f2bf(sv[i]); tb[i] = f2bf(tv[i]);
    }
    uint4 spk, tpk;
    spk.x = (u32)sb[0] | ((u32)sb[1] << 16); spk.y = (u32)sb[2] | ((u32)sb[3] << 16);
    spk.z = (u32)sb[4] | ((u32)sb[5] << 16); spk.w = (u32)sb[6] | ((u32)sb[7] << 16);
    tpk.x = (u32)tb[0] | ((u32)tb[1] << 16); tpk.y = (u32)tb[2] | ((u32)tb[3] << 16);
    tpk.z = (u32)tb[4] | ((u32)tb[5] << 16); tpk.w = (u32)tb[6] | ((u32)tb[7] << 16);
    const size_t chunk = ((size_t)tt*32 + ks)*64 + lane;   // lane-contiguous 1KB store
    ((uint4*)sbf)[chunk] = spk;
    ((uint4*)tbf)[chunk] = tpk;
  }

  x2  += __shfl_xor(x2, 32);
  sd2 += __shfl_xor(sd2, 32);
  nd2 += __shfl_xor(nd2, 32);

  __shared__ float st[3][4][32];
  if (lane < 32){ st[0][w][sp] = x2; st[1][w][sp] = sd2; st[2][w][sp] = nd2; }
  __syncthreads();
  if (tid < 32){
    float X2 = st[0][0][tid]+st[0][1][tid]+st[0][2][tid]+st[0][3][tid];
    float SD = st[1][0][tid]+st[1][1][tid]+st[1][2][tid]+st[1][3][tid];
    float ND = st[2][0][tid]+st[2][1][tid]+st[2][2][tid]+st[2][3][tid];
    int n2 = tt*32 + tid, b2 = n2 / T_N, tk2 = n2 - b2*T_N;
    x2s[n2] = X2;
    int valid = lengths[b2] / STRD; if (valid > T_N) valid = T_N;
    float mf = (tk2 < valid) ? 1.f : 0.f;
    float fp = mf * SD * (1.f/512.f);
    float tp = mf * fmaxf(sqrtf(SD) - sqrtf(ND) + 0.2f, 0.f);
#pragma unroll
    for (int mm = 1; mm < 32; mm <<= 1){ fp += __shfl_xor(fp, mm); tp += __shfl_xor(tp, mm); }
    if (tid == 0){ featP[tt] = fp; tripP[tt] = tp; }
  }
}

// ============ prep 2: codebook norms + bf16 cast, fragment layout ============
__global__ __launch_bounds__(64) void prep_cb_kernel(
    const float* __restrict__ cb, u16* __restrict__ cbbf, float* __restrict__ c2)
{
  const int lane = threadIdx.x, kh = lane >> 5, sp = lane & 31;
  const int ctile = blockIdx.x;                       // 0..127
  const int ch = ctile >> 6, ci = (ctile >> 4) & 3, ctg = ctile & 15;
  const int code = ctile*32 + sp;
  const float* crow = cb + (size_t)code * D_N;

  float s2 = 0.f;
#pragma unroll
  for (int stp = 0; stp < 32; ++stp){
    const int kc = stp >> 1, ks2 = stp & 1;
    const int k0 = stp*16 + kh*8;
    float4 c0 = *(const float4*)(crow + k0), c1 = *(const float4*)(crow + k0 + 4);
    float cv[8] = {c0.x,c0.y,c0.z,c0.w,c1.x,c1.y,c1.z,c1.w};
    u16 cbv[8];
#pragma unroll
    for (int i = 0; i < 8; ++i){ s2 += cv[i]*cv[i]; cbv[i] = f2bf(cv[i]); }
    uint4 pk;
    pk.x = (u32)cbv[0] | ((u32)cbv[1] << 16); pk.y = (u32)cbv[2] | ((u32)cbv[3] << 16);
    pk.z = (u32)cbv[4] | ((u32)cbv[5] << 16); pk.w = (u32)cbv[6] | ((u32)cbv[7] << 16);
    const size_t chunk = (size_t)((((ch*4+ci)*16 + kc)*16 + ctg)*2 + ks2)*64 + lane;
    ((uint4*)cbbf)[chunk] = pk;
  }
  s2 += __shfl_xor(s2, 32);
  if (lane < 32) c2[ctile*32 + lane] = s2;
}

// ============ main: 32x32x16 MFMA, codes=rows tokens=cols, A-from-global ============
// block: 256 thr, 32 tokens x 2048 codes (half codebook). grid 750 = 375 tiles x 2 halves.
// LDS: B double-buffer only (2 x 32KB). Per K-chunk(32): 16 MFMA/wave, 8 ds_read_b128,
// 4 global A-frag loads (prefetched), 8 gl_lds16/thread staging next chunk.
__global__ __launch_bounds__(256, 1) void main_kl_kernel(
    const u16* __restrict__ sbf, const u16* __restrict__ tbf,
    const u16* __restrict__ cbbf, const float* __restrict__ c2,
    float* __restrict__ stateP)
{
  __shared__ u16 Bb[2][16384];                        // 64 KB exactly

  const int tid = threadIdx.x;
  const int w = tid >> 6, lane = tid & 63;
  const int kh = lane >> 5;
  const int tt = blockIdx.x >> 1, ch = blockIdx.x & 1;

  const u16* sA  = sbf  + (size_t)tt*16384;
  const u16* tA  = tbf  + (size_t)tt*16384;
  const u16* cbB = cbbf + (size_t)ch*1048576;         // 2 MB half, 64 regions x 32KB

  // initial B stage: region 0 -> Bb[0]
#pragma unroll
  for (int r = 0; r < 8; ++r){
    const int off = (r*256 + tid)*8;
    gl_lds16(cbB + off, &Bb[0][off]);
  }
  // A prefetch for chunk 0 (K-steps 0,1)
  bf16x8 fS0 = *(const bf16x8*)(sA + (size_t)0*512 + lane*8);
  bf16x8 fS1 = *(const bf16x8*)(sA + (size_t)1*512 + lane*8);
  bf16x8 fT0 = *(const bf16x8*)(tA + (size_t)0*512 + lane*8);
  bf16x8 fT1 = *(const bf16x8*)(tA + (size_t)1*512 + lane*8);

  float mS = -3e38f, zS = 0.f, mT = -3e38f, zT = 0.f, aa = 0.f;
  f32x16 aS[4], aT[4];

  for (int chunk = 0; chunk < 64; ++chunk){
    const int ci = chunk >> 4, kc = chunk & 15;
    const int p = chunk & 1;
    if (kc == 0){
#pragma unroll
      for (int ct = 0; ct < 4; ++ct)
#pragma unroll
        for (int i = 0; i < 16; ++i){ aS[ct][i] = 0.f; aT[ct][i] = 0.f; }
    }
    __syncthreads();                                   // Bb[p] staged, Bb[p^1] free
    if (chunk < 63){
      const u16* src = cbB + (size_t)(chunk+1)*16384;
#pragma unroll
      for (int r = 0; r < 8; ++r){
        const int off = (r*256 + tid)*8;
        gl_lds16(src + off, &Bb[p^1][off]);
      }
    }
    // prefetch A fragments for next chunk (hidden under MFMAs)
    bf16x8 nS0 = fS0, nS1 = fS1, nT0 = fT0, nT1 = fT1;
    if (chunk < 63){
      const size_t ks2 = (size_t)((chunk+1) & 15)*2;
      nS0 = *(const bf16x8*)(sA + ks2*512 + lane*8);
      nS1 = *(const bf16x8*)(sA + (ks2+1)*512 + lane*8);
      nT0 = *(const bf16x8*)(tA + ks2*512 + lane*8);
      nT1 = *(const bf16x8*)(tA + (ks2+1)*512 + lane*8);
    }

    const u16* bp = &Bb[p][0];
#pragma unroll
    for (int ct = 0; ct < 4; ++ct){
      const int ctg = w*4 + ct;
      bf16x8 c0 = *(const bf16x8*)(bp + ctg*1024 + 0*512 + lane*8);
      bf16x8 c1 = *(const bf16x8*)(bp + ctg*1024 + 1*512 + lane*8);
      aS[ct] = __builtin_amdgcn_mfma_f32_32x32x16_bf16(c0, fS0, aS[ct], 0, 0, 0);
      aT[ct] = __builtin_amdgcn_mfma_f32_32x32x16_bf16(c0, fT0, aT[ct], 0, 0, 0);
      aS[ct] = __builtin_amdgcn_mfma_f32_32x32x16_bf16(c1, fS1, aS[ct], 0, 0, 0);
      aT[ct] = __builtin_amdgcn_mfma_f32_32x32x16_bf16(c1, fT1, aT[ct], 0, 0, 0);
    }
    fS0 = nS0; fS1 = nS1; fT0 = nT0; fT1 = nT1;

    if (kc == 15){
      // epilogue for this 512-code slab: batched online-softmax update
#pragma unroll
      for (int ct = 0; ct < 4; ++ct){
        const int ctg = w*4 + ct;
        const float* c2b = c2 + ch*2048 + ci*512 + ctg*32 + kh*4;
        float4 g0 = *(const float4*)(c2b);
        float4 g1 = *(const float4*)(c2b + 8);
        float4 g2 = *(const float4*)(c2b + 16);
        float4 g3 = *(const float4*)(c2b + 24);
        float c2v[16] = {g0.x,g0.y,g0.z,g0.w, g1.x,g1.y,g1.z,g1.w,
                         g2.x,g2.y,g2.z,g2.w, g3.x,g3.y,g3.z,g3.w};
        float sl[16], tl[16];
#pragma unroll
        for (int i = 0; i < 16; ++i){
          sl[i] = 2.0f*aS[ct][i] - c2v[i];
          tl[i] = 2.0f*aT[ct][i] - c2v[i];
        }
        float ms_t = sl[0], mt_t = tl[0];
#pragma unroll
        for (int i = 1; i < 16; ++i){ ms_t = fmaxf(ms_t, sl[i]); mt_t = fmaxf(mt_t, tl[i]); }
        float nmS = fmaxf(mS, ms_t), nmT = fmaxf(mT, mt_t);
        float esS = __expf(mS - nmS), esT = __expf(mT - nmT);
        zS *= esS; zT *= esT; aa *= esT;
#pragma unroll
        for (int i = 0; i < 16; ++i){
          zS += __expf(sl[i] - nmS);
          float e = __expf(tl[i] - nmT);
          zT += e; aa += e*(tl[i] - sl[i]);
        }
        mS = nmS; mT = nmT;
      }
    }
  }

  // merge the two k-halves (same token = lane&31, disjoint code rows)
  {
    float om = __shfl_xor(mS, 32), oZ = __shfl_xor(zS, 32);
    merge_state(mS, zS, om, oZ);
    float omt = __shfl_xor(mT, 32), ozt = __shfl_xor(zT, 32), oA = __shfl_xor(aa, 32);
    merge_stateT(mT, zT, aa, omt, ozt, oA);
  }
  __syncthreads();                                     // Bb dead; reuse as merge buffer
  float* wst = (float*)&Bb[0][0];                      // [4][32][5]
  if (lane < 32){
    float* pw = wst + (w*32 + lane)*5;
    pw[0] = mS; pw[1] = zS; pw[2] = mT; pw[3] = zT; pw[4] = aa;
  }
  __syncthreads();
  if (tid < 32){
    const float* p0 = wst + tid*5;
    float m_s = p0[0], z_s = p0[1], m_t = p0[2], z_t = p0[3], a = p0[4];
#pragma unroll
    for (int ww = 1; ww < 4; ++ww){
      const float* pw = wst + (ww*32 + tid)*5;
      merge_state(m_s, z_s, pw[0], pw[1]);
      merge_stateT(m_t, z_t, a, pw[2], pw[3], pw[4]);
    }
    const int n = tt*32 + tid;
    stateP[0*24000 + ch*12000 + n] = m_s;
    stateP[1*24000 + ch*12000 + n] = z_s;
    stateP[2*24000 + ch*12000 + n] = m_t;
    stateP[3*24000 + ch*12000 + n] = z_t;
    stateP[4*24000 + ch*12000 + n] = a;
  }
}

// ============ merge: combine the two code-halves per token; KL + min-dist ============
__global__ __launch_bounds__(256) void merge_kernel(
    const float* __restrict__ stateP, const float* __restrict__ x2s,
    const int* __restrict__ lengths,
    float* __restrict__ softP2, float* __restrict__ commP2)
{
  const int tid = threadIdx.x;
  const int n = blockIdx.x*256 + tid;
  float kl = 0.f, md = 0.f;
  if (n < NTOK){
    float m_s = stateP[0*24000 + n], z_s = stateP[1*24000 + n];
    float m_t = stateP[2*24000 + n], z_t = stateP[3*24000 + n], a = stateP[4*24000 + n];
    merge_state(m_s, z_s, stateP[0*24000 + 12000 + n], stateP[1*24000 + 12000 + n]);
    merge_stateT(m_t, z_t, a, stateP[2*24000 + 12000 + n], stateP[3*24000 + 12000 + n],
                 stateP[4*24000 + 12000 + n]);
    float klv = a / z_t - (m_t + __logf(z_t)) + (m_s + __logf(z_s));
    int b = n / T_N, tk = n - b*T_N;
    int valid = lengths[b] / STRD; if (valid > T_N) valid = T_N;
    kl = (tk < valid) ? klv : 0.f;
    md = fmaxf(x2s[n] - m_s, 0.f);                     // min ||x-c||^2
  }
#pragma unroll
  for (int mm = 1; mm < 64; mm <<= 1){ kl += __shfl_xor(kl, mm); md += __shfl_xor(md, mm); }
  __shared__ float rb[2][4];
  if ((tid & 63) == 0){ rb[0][tid>>6] = kl; rb[1][tid>>6] = md; }
  __syncthreads();
  if (tid == 0){
    softP2[blockIdx.x] = rb[0][0]+rb[0][1]+rb[0][2]+rb[0][3];
    commP2[blockIdx.x] = rb[1][0]+rb[1][1]+rb[1][2]+rb[1][3];
  }
}

// ============ finalize: deterministic double reduction ============
__global__ __launch_bounds__(256) void finalize_kernel(
    const float* __restrict__ featP, const float* __restrict__ tripP,
    const float* __restrict__ softP2, const float* __restrict__ commP2,
    const int* __restrict__ lengths, float* __restrict__ out)
{
  const int tid = threadIdx.x;
  double f = 0.0, tr = 0.0, sf = 0.0, cm = 0.0;
  for (int i = tid; i < 375; i += 256){ f += (double)featP[i]; tr += (double)tripP[i]; }
  for (int i = tid; i < 47;  i += 256){ sf += (double)softP2[i]; cm += (double)commP2[i]; }
#pragma unroll
  for (int mm = 1; mm < 64; mm <<= 1){
    f  += __shfl_xor(f,  mm); tr += __shfl_xor(tr, mm);
    sf += __shfl_xor(sf, mm); cm += __shfl_xor(cm, mm);
  }
  __shared__ double red[4][4];
  const int w = tid >> 6, lane = tid & 63;
  if (lane == 0){ red[w][0]=f; red[w][1]=tr; red[w][2]=sf; red[w][3]=cm; }
  __syncthreads();
  if (tid == 0){
    double F=0,TR=0,SF=0,CM=0;
    for (int ww = 0; ww < 4; ++ww){ F+=red[ww][0]; TR+=red[ww][1]; SF+=red[ww][2]; CM+=red[ww][3]; }
    long msum = 0;
    for (int b = 0; b < 8; ++b){ int v = lengths[b] / STRD; if (v > T_N) v = T_N; msum += v; }
    double inv = 1.0 / (double)msum;
    double total = F*inv + TR*inv + SF*inv + 0.2 * CM / ((double)B_N * T_N * D_N);
    out[0] = (float)total;
  }
}

extern "C" void kernel_launch(void* const* d_in, const int* in_sizes, int n_in,
                              void* d_out, int out_size, void* d_ws, size_t ws_size,
                              hipStream_t stream)
{
  const float* s  = (const float*)d_in[0];
  const float* t  = (const float*)d_in[1];
  // d_in[2] = teacher_codes: unused by the reference computation
  const float* cb = (const float*)d_in[3];
  const int* lengths = (const int*)d_in[4];

  char* ws = (char*)d_ws;
  float* x2s    = (float*)(ws + X2S_OFF);
  float* c2     = (float*)(ws + C2_OFF);
  float* featP  = (float*)(ws + FEATP_OFF);
  float* tripP  = (float*)(ws + TRIPP_OFF);
  float* softP2 = (float*)(ws + SOFTP2_OFF);
  float* commP2 = (float*)(ws + COMMP2_OFF);
  float* stateP = (float*)(ws + STATEP_OFF);
  u16* sbf  = (u16*)(ws + SBF_OFF);
  u16* tbf  = (u16*)(ws + TBF_OFF);
  u16* cbbf = (u16*)(ws + CBBF_OFF);

  prep_feat_kernel<<<375, 256, 0, stream>>>(s, t, lengths, sbf, tbf, x2s, featP, tripP);
  prep_cb_kernel<<<128, 64, 0, stream>>>(cb, cbbf, c2);
  main_kl_kernel<<<750, 256, 0, stream>>>(sbf, tbf, cbbf, c2, stateP);
  merge_kernel<<<47, 256, 0, stream>>>(stateP, x2s, lengths, softP2, commP2);
  finalize_kernel<<<1, 256, 0, stream>>>(featP, tripP, softP2, commP2, lengths, (float*)d_out);
}

// Round 4
// 266.376 us; speedup vs baseline: 1.1038x; 1.1038x over previous
//
#include <hip/hip_runtime.h>

typedef unsigned short u16;
typedef unsigned int   u32;
typedef float  f32x16 __attribute__((ext_vector_type(16)));
typedef __bf16 bf16x8 __attribute__((ext_vector_type(8)));

#define B_N   8
#define T_N   1500
#define D_N   512
#define K_N   4096
#define NTOK  12000
#define STRD  320

// ---- workspace byte offsets ----
#define X2S_OFF     0u          // 12000 f
#define C2_OFF      49152u      // 4096 f
#define FEATP_OFF   65536u      // 375 f
#define TRIPP_OFF   67584u      // 375 f
#define STATEP_OFF  71680u      // 5*2*12000 f
#define SBF_OFF     557056u     // 375 tiles * 32KB
#define TBF_OFF     (557056u + 12288000u)
#define CBBF_OFF    (557056u + 24576000u)   // 4 MB

// ---- global bf16 layouts, 16B chunks of 8 consecutive k ----
// sbf/tbf: chunk = (tt*32 + ks)*64 + kh*32 + sp   (token=tt*32+sp, k=ks*16+kh*8+j)
// cbbf: region r = ch*128 + cg*16 + kc (16KB each); within region (u16):
//       off = ctg*1024 + ks2*512 + kh*256 + sp*8
//       (code = ch*2048+cg*256+ctg*32+sp, k = kc*32+ks2*16+kh*8+j)

__device__ __forceinline__ u16 f2bf(float x){
  u32 u = __float_as_uint(x);
  u32 r = (u + 0x7fffu + ((u >> 16) & 1u)) >> 16;   // RNE
  return (u16)r;
}

__device__ __forceinline__ void gl_lds16(const void* g, void* l){
  __builtin_amdgcn_global_load_lds(
      (__attribute__((address_space(1))) void*)(g),
      (__attribute__((address_space(3))) void*)(l),
      16, 0, 0);
}

__device__ __forceinline__ void merge_state(float& m, float& Z, float om, float oZ){
  float nm = fmaxf(m, om);
  Z = Z*__expf(m - nm) + oZ*__expf(om - nm);
  m = nm;
}
__device__ __forceinline__ void merge_stateT(float& m, float& Z, float& A,
                                             float om, float oZ, float oA){
  float nm = fmaxf(m, om);
  float e0 = __expf(m - nm), e1 = __expf(om - nm);
  Z = Z*e0 + oZ*e1; A = A*e0 + oA*e1; m = nm;
}

// ============ prep: blocks 0..374 tokens; 375..406 codebook ============
__global__ __launch_bounds__(256) void prep_kernel(
    const float* __restrict__ s, const float* __restrict__ t,
    const float* __restrict__ cb, const int* __restrict__ lengths,
    u16* __restrict__ sbf, u16* __restrict__ tbf, u16* __restrict__ cbbf,
    float* __restrict__ x2s, float* __restrict__ c2,
    float* __restrict__ featP, float* __restrict__ tripP)
{
  const int tid = threadIdx.x;
  const int w = tid >> 6, lane = tid & 63;
  __shared__ float sred[3][32];

  if (blockIdx.x < 375){
    // ---- token path: 32 tokens, register transpose, coalesced both ways ----
    const int tt = blockIdx.x;
    const int t8 = lane >> 3, kpart = lane & 7;
    const int tokL = w*8 + t8;                  // 0..31
    const int n = tt*32 + tokL;
    const int b = n / T_N, tok = n - b*T_N;
    const int nr = ((b+7)&7)*T_N + tok;         // roll(teacher,+1,axis=0)
    const float* srow = s + (size_t)n  * D_N;
    const float* trow = t + (size_t)n  * D_N;
    const float* rrow = t + (size_t)nr * D_N;

    float x2 = 0.f, sd2 = 0.f, nd2 = 0.f;
    uint4 sbq[8], tbq[8];
#pragma unroll
    for (int q = 0; q < 8; ++q){
      const int kl = q*64 + kpart*8;            // 8 consecutive floats
      float4 a0 = *(const float4*)(srow + kl), a1 = *(const float4*)(srow + kl + 4);
      float4 b0 = *(const float4*)(trow + kl), b1 = *(const float4*)(trow + kl + 4);
      float4 r0 = *(const float4*)(rrow + kl), r1 = *(const float4*)(rrow + kl + 4);
      float sv[8] = {a0.x,a0.y,a0.z,a0.w,a1.x,a1.y,a1.z,a1.w};
      float tv[8] = {b0.x,b0.y,b0.z,b0.w,b1.x,b1.y,b1.z,b1.w};
      float rv[8] = {r0.x,r0.y,r0.z,r0.w,r1.x,r1.y,r1.z,r1.w};
      u16 sb[8], tb[8];
#pragma unroll
      for (int i = 0; i < 8; ++i){
        float d = sv[i] - tv[i]; sd2 += d*d;
        x2 += sv[i]*sv[i];
        float e = sv[i] - rv[i]; nd2 += e*e;
        sb[i] = f2bf(sv[i]); tb[i] = f2bf(tv[i]);
      }
      sbq[q].x = (u32)sb[0] | ((u32)sb[1]<<16); sbq[q].y = (u32)sb[2] | ((u32)sb[3]<<16);
      sbq[q].z = (u32)sb[4] | ((u32)sb[5]<<16); sbq[q].w = (u32)sb[6] | ((u32)sb[7]<<16);
      tbq[q].x = (u32)tb[0] | ((u32)tb[1]<<16); tbq[q].y = (u32)tb[2] | ((u32)tb[3]<<16);
      tbq[q].z = (u32)tb[4] | ((u32)tb[5]<<16); tbq[q].w = (u32)tb[6] | ((u32)tb[7]<<16);
    }
    // stores: thread's chunk q has k = q*64+kpart*8 -> ks = q*4 + (kpart>>1), kh = kpart&1
#pragma unroll
    for (int q = 0; q < 8; ++q){
      const int ks = q*4 + (kpart >> 1), kh = kpart & 1;
      const size_t chunk = ((size_t)tt*32 + ks)*64 + kh*32 + tokL;
      ((uint4*)sbf)[chunk] = sbq[q];
      ((uint4*)tbf)[chunk] = tbq[q];
    }
    // stats: reduce over kpart (lanes xor 1,2,4)
#pragma unroll
    for (int mm = 1; mm < 8; mm <<= 1){
      x2  += __shfl_xor(x2,  mm);
      sd2 += __shfl_xor(sd2, mm);
      nd2 += __shfl_xor(nd2, mm);
    }
    if (kpart == 0){ sred[0][tokL] = x2; sred[1][tokL] = sd2; sred[2][tokL] = nd2; }
    __syncthreads();
    if (tid < 32){
      float X2 = sred[0][tid], SD = sred[1][tid], ND = sred[2][tid];
      int n2 = tt*32 + tid, b2 = n2 / T_N, tk2 = n2 - b2*T_N;
      x2s[n2] = X2;
      int valid = lengths[b2] / STRD; if (valid > T_N) valid = T_N;
      float mf = (tk2 < valid) ? 1.f : 0.f;
      float fp = mf * SD * (1.f/512.f);
      float tp = mf * fmaxf(sqrtf(SD) - sqrtf(ND) + 0.2f, 0.f);
#pragma unroll
      for (int mm = 1; mm < 32; mm <<= 1){ fp += __shfl_xor(fp, mm); tp += __shfl_xor(tp, mm); }
      if (tid == 0){ featP[tt] = fp; tripP[tt] = tp; }
    }
  } else {
    // ---- codebook path: wave = one 32-code group ----
    const int idx = blockIdx.x - 375;
    const int ctile = idx*4 + w;                // 0..127
    const int kh = lane >> 5, sp = lane & 31;
    const int ch = ctile >> 6, cg = (ctile >> 3) & 7, ctg = ctile & 7;
    const int code = ctile*32 + sp;
    const float* crow = cb + (size_t)code * D_N;

    float s2 = 0.f;
#pragma unroll
    for (int stp = 0; stp < 32; ++stp){
      const int kc = stp >> 1, ks2 = stp & 1;
      const int k0 = stp*16 + kh*8;
      float4 c0 = *(const float4*)(crow + k0), c1 = *(const float4*)(crow + k0 + 4);
      float cv[8] = {c0.x,c0.y,c0.z,c0.w,c1.x,c1.y,c1.z,c1.w};
      u16 cbv[8];
#pragma unroll
      for (int i = 0; i < 8; ++i){ s2 += cv[i]*cv[i]; cbv[i] = f2bf(cv[i]); }
      uint4 pk;
      pk.x = (u32)cbv[0] | ((u32)cbv[1]<<16); pk.y = (u32)cbv[2] | ((u32)cbv[3]<<16);
      pk.z = (u32)cbv[4] | ((u32)cbv[5]<<16); pk.w = (u32)cbv[6] | ((u32)cbv[7]<<16);
      const size_t off = ((size_t)(ch*128 + cg*16 + kc))*8192 + ctg*1024 + ks2*512 + lane*8;
      *(uint4*)(cbbf + off) = pk;
    }
    s2 += __shfl_xor(s2, 32);
    if (lane < 32) c2[ctile*32 + lane] = s2;
  }
}

// ============ main: 32x32x16, codes=rows tokens=cols, 16KB dbuf chunks ============
// block: 256 thr, 32 tokens x 2048 codes (half codebook). grid 750. LDS 32KB -> 3 blk/CU.
__global__ __launch_bounds__(256, 3) void main_kl_kernel(
    const u16* __restrict__ sbf, const u16* __restrict__ tbf,
    const u16* __restrict__ cbbf, const float* __restrict__ c2,
    float* __restrict__ stateP)
{
  __shared__ u16 Bb[2][8192];                   // 32 KB

  const int tid = threadIdx.x;
  const int w = tid >> 6, lane = tid & 63;
  const int kh = lane >> 5;
  const int tt = blockIdx.x >> 1, ch = blockIdx.x & 1;

  const u16* sA  = sbf  + (size_t)tt*16384;
  const u16* tA  = tbf  + (size_t)tt*16384;
  const u16* cbB = cbbf + (size_t)ch*1048576;   // 128 regions x 8192 u16

  // stage region 0
#pragma unroll
  for (int r = 0; r < 4; ++r){
    const int off = (r*256 + tid)*8;
    gl_lds16(cbB + off, &Bb[0][off]);
  }
  // A frags for chunk 0 (kc=0)
  bf16x8 fS0 = *(const bf16x8*)(sA + lane*8);
  bf16x8 fS1 = *(const bf16x8*)(sA + 512 + lane*8);
  bf16x8 fT0 = *(const bf16x8*)(tA + lane*8);
  bf16x8 fT1 = *(const bf16x8*)(tA + 512 + lane*8);

  float mS = -3e38f, zS = 0.f, mT = -3e38f, zT = 0.f, aa = 0.f;
  f32x16 aS0, aS1, aT0, aT1;

  for (int c = 0; c < 128; ++c){
    const int kc = c & 15, p = c & 1;
    if (kc == 0){
#pragma unroll
      for (int i = 0; i < 16; ++i){ aS0[i]=0.f; aS1[i]=0.f; aT0[i]=0.f; aT1[i]=0.f; }
    }
    __syncthreads();                            // Bb[p] staged; Bb[p^1] consumed
    if (c < 127){
      const u16* src = cbB + (size_t)(c+1)*8192;
#pragma unroll
      for (int r = 0; r < 4; ++r){
        const int off = (r*256 + tid)*8;
        gl_lds16(src + off, &Bb[p^1][off]);
      }
    }
    // prefetch next chunk's A frags (L2-hot after first cg pass)
    bf16x8 nS0 = fS0, nS1 = fS1, nT0 = fT0, nT1 = fT1;
    if (c < 127){
      const size_t kb = (size_t)((c+1) & 15) * 1024;
      nS0 = *(const bf16x8*)(sA + kb + lane*8);
      nS1 = *(const bf16x8*)(sA + kb + 512 + lane*8);
      nT0 = *(const bf16x8*)(tA + kb + lane*8);
      nT1 = *(const bf16x8*)(tA + kb + 512 + lane*8);
    }

    const u16* bp = &Bb[p][0];
    {
      bf16x8 c0 = *(const bf16x8*)(bp + (w*2+0)*1024 + lane*8);
      bf16x8 c1 = *(const bf16x8*)(bp + (w*2+0)*1024 + 512 + lane*8);
      aS0 = __builtin_amdgcn_mfma_f32_32x32x16_bf16(c0, fS0, aS0, 0, 0, 0);
      aT0 = __builtin_amdgcn_mfma_f32_32x32x16_bf16(c0, fT0, aT0, 0, 0, 0);
      aS0 = __builtin_amdgcn_mfma_f32_32x32x16_bf16(c1, fS1, aS0, 0, 0, 0);
      aT0 = __builtin_amdgcn_mfma_f32_32x32x16_bf16(c1, fT1, aT0, 0, 0, 0);
    }
    {
      bf16x8 c0 = *(const bf16x8*)(bp + (w*2+1)*1024 + lane*8);
      bf16x8 c1 = *(const bf16x8*)(bp + (w*2+1)*1024 + 512 + lane*8);
      aS1 = __builtin_amdgcn_mfma_f32_32x32x16_bf16(c0, fS0, aS1, 0, 0, 0);
      aT1 = __builtin_amdgcn_mfma_f32_32x32x16_bf16(c0, fT0, aT1, 0, 0, 0);
      aS1 = __builtin_amdgcn_mfma_f32_32x32x16_bf16(c1, fS1, aS1, 0, 0, 0);
      aT1 = __builtin_amdgcn_mfma_f32_32x32x16_bf16(c1, fT1, aT1, 0, 0, 0);
    }
    fS0 = nS0; fS1 = nS1; fT0 = nT0; fT1 = nT1;

    if (kc == 15){
      const int cg = c >> 4;
#pragma unroll
      for (int ct = 0; ct < 2; ++ct){
        const f32x16& vS = ct ? aS1 : aS0;
        const f32x16& vT = ct ? aT1 : aT0;
        const int ctg = w*2 + ct;
        const float* c2b = c2 + ch*2048 + cg*256 + ctg*32 + kh*4;
        float4 g0 = *(const float4*)(c2b);
        float4 g1 = *(const float4*)(c2b + 8);
        float4 g2 = *(const float4*)(c2b + 16);
        float4 g3 = *(const float4*)(c2b + 24);
        float c2v[16] = {g0.x,g0.y,g0.z,g0.w, g1.x,g1.y,g1.z,g1.w,
                         g2.x,g2.y,g2.z,g2.w, g3.x,g3.y,g3.z,g3.w};
        float sl[16], tl[16];
#pragma unroll
        for (int i = 0; i < 16; ++i){
          sl[i] = 2.0f*vS[i] - c2v[i];
          tl[i] = 2.0f*vT[i] - c2v[i];
        }
        float ms_t = sl[0], mt_t = tl[0];
#pragma unroll
        for (int i = 1; i < 16; ++i){ ms_t = fmaxf(ms_t, sl[i]); mt_t = fmaxf(mt_t, tl[i]); }
        float nmS = fmaxf(mS, ms_t), nmT = fmaxf(mT, mt_t);
        float esS = __expf(mS - nmS), esT = __expf(mT - nmT);
        zS *= esS; zT *= esT; aa *= esT;
#pragma unroll
        for (int i = 0; i < 16; ++i){
          zS += __expf(sl[i] - nmS);
          float e = __expf(tl[i] - nmT);
          zT += e; aa += e*(tl[i] - sl[i]);
        }
        mS = nmS; mT = nmT;
      }
    }
  }

  // merge kh halves (same token, disjoint code rows)
  {
    float om = __shfl_xor(mS, 32), oZ = __shfl_xor(zS, 32);
    merge_state(mS, zS, om, oZ);
    float omt = __shfl_xor(mT, 32), ozt = __shfl_xor(zT, 32), oA = __shfl_xor(aa, 32);
    merge_stateT(mT, zT, aa, omt, ozt, oA);
  }
  __syncthreads();                               // Bb dead; reuse as merge buffer
  float* wst = (float*)&Bb[0][0];                // [4][32][5]
  if (lane < 32){
    float* pw = wst + (w*32 + lane)*5;
    pw[0] = mS; pw[1] = zS; pw[2] = mT; pw[3] = zT; pw[4] = aa;
  }
  __syncthreads();
  if (tid < 32){
    const float* p0 = wst + tid*5;
    float m_s = p0[0], z_s = p0[1], m_t = p0[2], z_t = p0[3], a = p0[4];
#pragma unroll
    for (int ww = 1; ww < 4; ++ww){
      const float* pw = wst + (ww*32 + tid)*5;
      merge_state(m_s, z_s, pw[0], pw[1]);
      merge_stateT(m_t, z_t, a, pw[2], pw[3], pw[4]);
    }
    const int n = tt*32 + tid;
    stateP[0*24000 + ch*12000 + n] = m_s;
    stateP[1*24000 + ch*12000 + n] = z_s;
    stateP[2*24000 + ch*12000 + n] = m_t;
    stateP[3*24000 + ch*12000 + n] = z_t;
    stateP[4*24000 + ch*12000 + n] = a;
  }
}

// ============ tail: merge halves + KL/min-dist + full reduction, 1 block ============
__global__ __launch_bounds__(1024) void tail_kernel(
    const float* __restrict__ stateP, const float* __restrict__ x2s,
    const float* __restrict__ featP, const float* __restrict__ tripP,
    const int* __restrict__ lengths, float* __restrict__ out)
{
  const int tid = threadIdx.x;
  double kl_s = 0.0, md_s = 0.0, f = 0.0, tr = 0.0;
  for (int n = tid; n < NTOK; n += 1024){
    float m_s = stateP[0*24000 + n], z_s = stateP[1*24000 + n];
    float m_t = stateP[2*24000 + n], z_t = stateP[3*24000 + n], a = stateP[4*24000 + n];
    merge_state(m_s, z_s, stateP[0*24000 + 12000 + n], stateP[1*24000 + 12000 + n]);
    merge_stateT(m_t, z_t, a, stateP[2*24000 + 12000 + n], stateP[3*24000 + 12000 + n],
                 stateP[4*24000 + 12000 + n]);
    float klv = a / z_t - (m_t + __logf(z_t)) + (m_s + __logf(z_s));
    int b = n / T_N, tk = n - b*T_N;
    int valid = lengths[b] / STRD; if (valid > T_N) valid = T_N;
    if (tk < valid) kl_s += (double)klv;
    md_s += (double)fmaxf(x2s[n] - m_s, 0.f);
  }
  for (int i = tid; i < 375; i += 1024){ f += (double)featP[i]; tr += (double)tripP[i]; }
#pragma unroll
  for (int mm = 1; mm < 64; mm <<= 1){
    kl_s += __shfl_xor(kl_s, mm); md_s += __shfl_xor(md_s, mm);
    f    += __shfl_xor(f,    mm); tr   += __shfl_xor(tr,   mm);
  }
  __shared__ double red[16][4];
  const int w = tid >> 6, lane = tid & 63;
  if (lane == 0){ red[w][0]=kl_s; red[w][1]=md_s; red[w][2]=f; red[w][3]=tr; }
  __syncthreads();
  if (tid == 0){
    double KL=0, MD=0, F=0, TR=0;
    for (int ww = 0; ww < 16; ++ww){ KL+=red[ww][0]; MD+=red[ww][1]; F+=red[ww][2]; TR+=red[ww][3]; }
    long msum = 0;
    for (int b = 0; b < 8; ++b){ int v = lengths[b] / STRD; if (v > T_N) v = T_N; msum += v; }
    double inv = 1.0 / (double)msum;
    double total = F*inv + TR*inv + KL*inv + 0.2 * MD / ((double)B_N * T_N * D_N);
    out[0] = (float)total;
  }
}

extern "C" void kernel_launch(void* const* d_in, const int* in_sizes, int n_in,
                              void* d_out, int out_size, void* d_ws, size_t ws_size,
                              hipStream_t stream)
{
  const float* s  = (const float*)d_in[0];
  const float* t  = (const float*)d_in[1];
  // d_in[2] = teacher_codes: unused by the reference computation
  const float* cb = (const float*)d_in[3];
  const int* lengths = (const int*)d_in[4];

  char* ws = (char*)d_ws;
  float* x2s    = (float*)(ws + X2S_OFF);
  float* c2     = (float*)(ws + C2_OFF);
  float* featP  = (float*)(ws + FEATP_OFF);
  float* tripP  = (float*)(ws + TRIPP_OFF);
  float* stateP = (float*)(ws + STATEP_OFF);
  u16* sbf  = (u16*)(ws + SBF_OFF);
  u16* tbf  = (u16*)(ws + TBF_OFF);
  u16* cbbf = (u16*)(ws + CBBF_OFF);

  prep_kernel<<<407, 256, 0, stream>>>(s, t, cb, lengths, sbf, tbf, cbbf,
                                       x2s, c2, featP, tripP);
  main_kl_kernel<<<750, 256, 0, stream>>>(sbf, tbf, cbbf, c2, stateP);
  tail_kernel<<<1, 1024, 0, stream>>>(stateP, x2s, featP, tripP, lengths, (float*)d_out);
}